// Round 3
// baseline (158.980 us; speedup 1.0000x reference)
//
#include <hip/hip_runtime.h>

#define NODES 50000
#define NA    65
#define NDEG  32

// Inputs verified f32 (Round-2 probe: flag=0). Output f32.
// Decomposition: 4 threads per node, each owns 8 of 32 output channels.
// Folded first layer: relu(rel @ (W_se@W1) + (b_se@W1 + b1)) : 2 -> 16.
// relu(max) fold: vmax starts at 0, second-layer relu folds into the max.
// Scatter/-inf in the reference is dense & unique by construction -> plain max.

static __device__ __forceinline__ void mlp_step(float r0, float r1,
                                                const float* Wc0, const float* Wc1,
                                                const float* bc, const float* W2l,
                                                const float* b2l, float* vmax) {
    float h1[16];
#pragma unroll
    for (int j = 0; j < 16; ++j)
        h1[j] = fmaxf(0.0f, fmaf(r0, Wc0[j], fmaf(r1, Wc1[j], bc[j])));
#pragma unroll
    for (int i = 0; i < 8; ++i) {
        float s = b2l[i];
#pragma unroll
        for (int j = 0; j < 16; ++j) s = fmaf(h1[j], W2l[j * 8 + i], s);
        vmax[i] = fmaxf(vmax[i], s);
    }
}

// __launch_bounds__(256,2): 2 waves/EU min -> 256-VGPR cap so the 184
// register-resident weights (W2l 128 + Wc/bc 48 + b2l 8) never reload.
// (Round-2 evidence: bare (256) capped at 124 VGPR -> W2 reloaded per chunk.)
__global__ __launch_bounds__(256, 2) void fused_kernel(
    const float* __restrict__ corr,   // (N, 65, 2)
    const int*   __restrict__ nei,    // (N, 32, 3)
    const float* __restrict__ W_se,   // (2, 32)
    const float* __restrict__ b_se,   // (32)
    const float* __restrict__ W1,     // (32, 16)
    const float* __restrict__ b1,     // (16)
    const float* __restrict__ W2,     // (16, 32)
    const float* __restrict__ b2,     // (32)
    float* __restrict__ out)          // (N, 32)
{
    // ---- per-block fold of W_se@W1 and b_se@W1+b1 (48 values) into LDS ----
    __shared__ __align__(16) float fold[48];
    int t = threadIdx.x;
    if (t < 48) {
        float s;
        if (t < 32) {                       // Wc[c][j], c = t>>4, j = t&15
            int c = t >> 4, j = t & 15;
            s = 0.0f;
#pragma unroll
            for (int e = 0; e < 32; ++e)
                s = fmaf(W_se[c * 32 + e], W1[e * 16 + j], s);
        } else {                            // bc[j]
            int j = t - 32;
            s = b1[j];
#pragma unroll
            for (int e = 0; e < 32; ++e)
                s = fmaf(b_se[e], W1[e * 16 + j], s);
        }
        fold[t] = s;
    }
    __syncthreads();

    int tid = blockIdx.x * 256 + t;
    if (tid >= NODES * 4) return;
    int n = tid >> 2, k0 = (tid & 3) * 8;

    // ---- weights -> registers ----
    float Wc0[16], Wc1[16], bc[16], W2l[128], b2l[8];
    {
        const float4* fv = (const float4*)fold;
#pragma unroll
        for (int j = 0; j < 4; ++j) {
            float4 x = fv[j], y = fv[4 + j], z = fv[8 + j];
            Wc0[4*j] = x.x; Wc0[4*j+1] = x.y; Wc0[4*j+2] = x.z; Wc0[4*j+3] = x.w;
            Wc1[4*j] = y.x; Wc1[4*j+1] = y.y; Wc1[4*j+2] = y.z; Wc1[4*j+3] = y.w;
            bc[4*j]  = z.x; bc[4*j+1]  = z.y; bc[4*j+2]  = z.z; bc[4*j+3]  = z.w;
        }
#pragma unroll
        for (int j = 0; j < 16; ++j) {
            const float4* p = (const float4*)(W2 + j * 32 + k0);
            float4 x = p[0], y = p[1];
            W2l[j*8+0] = x.x; W2l[j*8+1] = x.y; W2l[j*8+2] = x.z; W2l[j*8+3] = x.w;
            W2l[j*8+4] = y.x; W2l[j*8+5] = y.y; W2l[j*8+6] = y.z; W2l[j*8+7] = y.w;
        }
        const float4* p = (const float4*)(b2 + k0);
        float4 x = p[0], y = p[1];
        b2l[0] = x.x; b2l[1] = x.y; b2l[2] = x.z; b2l[3] = x.w;
        b2l[4] = y.x; b2l[5] = y.y; b2l[6] = y.z; b2l[7] = y.w;
    }

    float vmax[8];
#pragma unroll
    for (int i = 0; i < 8; ++i) vmax[i] = 0.0f;

    const float2* corrf = (const float2*)corr + (size_t)n * NA;
    const int*    neip  = nei + (size_t)n * (NDEG * 3) + 1;  // col1, stride 3

    // ---- software-pipelined gather: indices 2 chunks ahead, rel 1 ahead ----
    int aA[4], aB[4];
    float2 rA[4], rB[4];
#pragma unroll
    for (int u = 0; u < 4; ++u) aA[u] = neip[u * 3];
#pragma unroll
    for (int u = 0; u < 4; ++u) aB[u] = neip[(4 + u) * 3];
#pragma unroll
    for (int u = 0; u < 4; ++u) rA[u] = corrf[aA[u]];

#pragma unroll
    for (int c = 0; c < 8; c += 2) {
        // even chunk: compute rA; prefetch rB; refill aA with chunk c+2
#pragma unroll
        for (int u = 0; u < 4; ++u) rB[u] = corrf[aB[u]];
        if (c + 2 < 8) {
#pragma unroll
            for (int u = 0; u < 4; ++u) aA[u] = neip[((c + 2) * 4 + u) * 3];
        }
#pragma unroll
        for (int u = 0; u < 4; ++u)
            mlp_step(rA[u].x, rA[u].y, Wc0, Wc1, bc, W2l, b2l, vmax);

        // odd chunk: compute rB; prefetch rA (chunk c+2); refill aB (c+3)
        if (c + 2 < 8) {
#pragma unroll
            for (int u = 0; u < 4; ++u) rA[u] = corrf[aA[u]];
        }
        if (c + 3 < 8) {
#pragma unroll
            for (int u = 0; u < 4; ++u) aB[u] = neip[((c + 3) * 4 + u) * 3];
        }
#pragma unroll
        for (int u = 0; u < 4; ++u)
            mlp_step(rB[u].x, rB[u].y, Wc0, Wc1, bc, W2l, b2l, vmax);
    }

    // ---- coalesced f32 store: node n writes 32 floats, this thread 8 ----
    float* op = out + (size_t)n * 32 + k0;
    ((float4*)op)[0] = make_float4(vmax[0], vmax[1], vmax[2], vmax[3]);
    ((float4*)op)[1] = make_float4(vmax[4], vmax[5], vmax[6], vmax[7]);
}

extern "C" void kernel_launch(void* const* d_in, const int* in_sizes, int n_in,
                              void* d_out, int out_size, void* d_ws, size_t ws_size,
                              hipStream_t stream) {
    const float* corr = (const float*)d_in[0];
    const int*   nei  = (const int*)d_in[1];
    // d_in[2] = lstm_state: dead input (unused by the reference output)
    const float* W_se = (const float*)d_in[3];
    const float* b_se = (const float*)d_in[4];
    const float* W1   = (const float*)d_in[5];
    const float* b1   = (const float*)d_in[6];
    const float* W2   = (const float*)d_in[7];
    const float* b2   = (const float*)d_in[8];
    float* out = (float*)d_out;

    int total  = NODES * 4;
    int blocks = (total + 255) / 256;
    hipLaunchKernelGGL(fused_kernel, dim3(blocks), dim3(256), 0, stream,
                       corr, nei, W_se, b_se, W1, b1, W2, b2, out);
}

// Round 4
// 129.786 us; speedup vs baseline: 1.2249x; 1.2249x over previous
//
#include <hip/hip_runtime.h>

#define NODES 50000
#define NA    65
#define NDEG  32

// Inputs f32 (verified by Round-2 probe). Output f32.
// Decomposition: 8 threads per node, each owns 4 of 32 output channels.
//   - W2 slice = 16 rows x 4 ch = 16 NAMED float4 regs (no array -> no scratch;
//     Round-3 post-mortem: a float[128] array spilled 450B/thread to HBM).
//   - Folded layer 1: relu(rel @ (W_se@W1) + (b_se@W1 + b1)) : 2 -> 16.
//   - relu/max fold: vmax starts at 0; -inf scatter in ref is dense+unique.
// __launch_bounds__(256,1): loosest cap under either interpretation of arg2
// (Round 3: (256,2) produced a 128-VGPR cap + spill on this toolchain).

__global__ __launch_bounds__(256, 1) void fused_kernel(
    const float* __restrict__ corr,   // (N, 65, 2)
    const int*   __restrict__ nei,    // (N, 32, 3)
    const float* __restrict__ W_se,   // (2, 32)
    const float* __restrict__ b_se,   // (32)
    const float* __restrict__ W1,     // (32, 16)
    const float* __restrict__ b1,     // (16)
    const float* __restrict__ W2,     // (16, 32)
    const float* __restrict__ b2,     // (32)
    float* __restrict__ out)          // (N, 32)
{
    // ---- per-block fold of W_se@W1 (32) and b_se@W1+b1 (16) into LDS ----
    __shared__ __align__(16) float fold[48];
    int t = threadIdx.x;
    if (t < 48) {
        float s;
        if (t < 32) {                       // Wc[c][j]: c = t>>4, j = t&15
            int c = t >> 4, j = t & 15;
            s = 0.0f;
#pragma unroll
            for (int e = 0; e < 32; ++e)
                s = fmaf(W_se[c * 32 + e], W1[e * 16 + j], s);
        } else {                            // bc[j]
            int j = t - 32;
            s = b1[j];
#pragma unroll
            for (int e = 0; e < 32; ++e)
                s = fmaf(b_se[e], W1[e * 16 + j], s);
        }
        fold[t] = s;
    }
    __syncthreads();

    int tid = blockIdx.x * 256 + t;
    if (tid >= NODES * 8) return;
    int n  = tid >> 3;            // node
    int k0 = (tid & 7) * 4;       // 4-channel slice

    // ---- layer-1 weights -> registers (48 floats; fine at 124-VGPR in R2) ----
    float Wc0[16], Wc1[16], bc[16];
    {
        const float4* fv = (const float4*)fold;
#pragma unroll
        for (int j = 0; j < 4; ++j) {
            float4 x = fv[j], y = fv[4 + j], z = fv[8 + j];
            Wc0[4*j] = x.x; Wc0[4*j+1] = x.y; Wc0[4*j+2] = x.z; Wc0[4*j+3] = x.w;
            Wc1[4*j] = y.x; Wc1[4*j+1] = y.y; Wc1[4*j+2] = y.z; Wc1[4*j+3] = y.w;
            bc[4*j]  = z.x; bc[4*j+1]  = z.y; bc[4*j+2]  = z.z; bc[4*j+3]  = z.w;
        }
    }

    // ---- W2 4-channel slice: 16 NAMED float4 registers ----
#define W2LD(i) float4 w2_##i = *(const float4*)(W2 + (i) * 32 + k0)
    W2LD(0);  W2LD(1);  W2LD(2);  W2LD(3);
    W2LD(4);  W2LD(5);  W2LD(6);  W2LD(7);
    W2LD(8);  W2LD(9);  W2LD(10); W2LD(11);
    W2LD(12); W2LD(13); W2LD(14); W2LD(15);
#undef W2LD
    float4 b2v = *(const float4*)(b2 + k0);

    float4 vmax = make_float4(0.0f, 0.0f, 0.0f, 0.0f);

    const float2* corrf = (const float2*)corr + (size_t)n * NA;
    const int*    neip  = nei + (size_t)n * (NDEG * 3) + 1;   // col1, stride 3

#define L2ROW(i) do {                               \
        float hj = h1[i];                           \
        acc.x = fmaf(hj, w2_##i.x, acc.x);          \
        acc.y = fmaf(hj, w2_##i.y, acc.y);          \
        acc.z = fmaf(hj, w2_##i.z, acc.z);          \
        acc.w = fmaf(hj, w2_##i.w, acc.w);          \
    } while (0)

#define MLP_STEP(r0, r1) do {                                               \
        float h1[16];                                                       \
        _Pragma("unroll")                                                   \
        for (int j = 0; j < 16; ++j)                                        \
            h1[j] = fmaxf(0.0f, fmaf((r0), Wc0[j], fmaf((r1), Wc1[j], bc[j]))); \
        float4 acc = b2v;                                                   \
        L2ROW(0);  L2ROW(1);  L2ROW(2);  L2ROW(3);                          \
        L2ROW(4);  L2ROW(5);  L2ROW(6);  L2ROW(7);                          \
        L2ROW(8);  L2ROW(9);  L2ROW(10); L2ROW(11);                         \
        L2ROW(12); L2ROW(13); L2ROW(14); L2ROW(15);                         \
        vmax.x = fmaxf(vmax.x, acc.x);                                      \
        vmax.y = fmaxf(vmax.y, acc.y);                                      \
        vmax.z = fmaxf(vmax.z, acc.z);                                      \
        vmax.w = fmaxf(vmax.w, acc.w);                                      \
    } while (0)

    // ---- software-pipelined gather: idx 2 chunks ahead, rel 1 ahead ----
    int aA[4], aB[4];
    float2 rA[4], rB[4];
#pragma unroll
    for (int u = 0; u < 4; ++u) aA[u] = neip[u * 3];
#pragma unroll
    for (int u = 0; u < 4; ++u) aB[u] = neip[(4 + u) * 3];
#pragma unroll
    for (int u = 0; u < 4; ++u) rA[u] = corrf[aA[u]];

#pragma unroll
    for (int c = 0; c < 8; c += 2) {
#pragma unroll
        for (int u = 0; u < 4; ++u) rB[u] = corrf[aB[u]];
        if (c + 2 < 8) {
#pragma unroll
            for (int u = 0; u < 4; ++u) aA[u] = neip[((c + 2) * 4 + u) * 3];
        }
#pragma unroll
        for (int u = 0; u < 4; ++u) MLP_STEP(rA[u].x, rA[u].y);

        if (c + 2 < 8) {
#pragma unroll
            for (int u = 0; u < 4; ++u) rA[u] = corrf[aA[u]];
        }
        if (c + 3 < 8) {
#pragma unroll
            for (int u = 0; u < 4; ++u) aB[u] = neip[((c + 3) * 4 + u) * 3];
        }
#pragma unroll
        for (int u = 0; u < 4; ++u) MLP_STEP(rB[u].x, rB[u].y);
    }
#undef MLP_STEP
#undef L2ROW

    // ---- coalesced store: wave writes 64 x 16B contiguous ----
    *(float4*)(out + (size_t)n * 32 + k0) = vmax;
}

extern "C" void kernel_launch(void* const* d_in, const int* in_sizes, int n_in,
                              void* d_out, int out_size, void* d_ws, size_t ws_size,
                              hipStream_t stream) {
    const float* corr = (const float*)d_in[0];
    const int*   nei  = (const int*)d_in[1];
    // d_in[2] = lstm_state: dead input (unused by the reference output)
    const float* W_se = (const float*)d_in[3];
    const float* b_se = (const float*)d_in[4];
    const float* W1   = (const float*)d_in[5];
    const float* b1   = (const float*)d_in[6];
    const float* W2   = (const float*)d_in[7];
    const float* b2   = (const float*)d_in[8];
    float* out = (float*)d_out;

    int total  = NODES * 8;
    int blocks = (total + 255) / 256;
    hipLaunchKernelGGL(fused_kernel, dim3(blocks), dim3(256), 0, stream,
                       corr, nei, W_se, b_se, W1, b1, W2, b2, out);
}

// Round 5
// 125.453 us; speedup vs baseline: 1.2672x; 1.0345x over previous
//
#include <hip/hip_runtime.h>

#define NODES 50000
#define NA    65
#define NDEG  32

// Inputs f32 (verified R2 probe). Output f32.
// R4 -> R5: same decomposition (8 threads/node, 4 channels each), but all
// MLP math on float2 ext-vectors so the backend emits v_pk_fma_f32 /
// v_pk_max_f32 (2 lanes/instr, same 2-cyc issue) -> ~2x fewer VALU instr.
// W2 slice stays in NAMED v2f registers (R3: array form spilled to scratch).

typedef float v2f __attribute__((ext_vector_type(2)));

static __device__ __forceinline__ v2f splat2(float x) { v2f r; r.x = x; r.y = x; return r; }

static __device__ __forceinline__ v2f pk_fma(v2f a, v2f b, v2f c) {
#if __has_builtin(__builtin_elementwise_fma)
    return __builtin_elementwise_fma(a, b, c);
#else
    v2f r; r.x = fmaf(a.x, b.x, c.x); r.y = fmaf(a.y, b.y, c.y); return r;
#endif
}

static __device__ __forceinline__ v2f pk_max(v2f a, v2f b) {
#if __has_builtin(__builtin_elementwise_max)
    return __builtin_elementwise_max(a, b);
#else
    v2f r; r.x = fmaxf(a.x, b.x); r.y = fmaxf(a.y, b.y); return r;
#endif
}

__global__ __launch_bounds__(256, 1) void fused_kernel(
    const float* __restrict__ corr,   // (N, 65, 2)
    const int*   __restrict__ nei,    // (N, 32, 3)
    const float* __restrict__ W_se,   // (2, 32)
    const float* __restrict__ b_se,   // (32)
    const float* __restrict__ W1,     // (32, 16)
    const float* __restrict__ b1,     // (16)
    const float* __restrict__ W2,     // (16, 32)
    const float* __restrict__ b2,     // (32)
    float* __restrict__ out)          // (N, 32)
{
    // ---- per-block fold of W_se@W1 (32) and b_se@W1+b1 (16) into LDS ----
    __shared__ __align__(16) float fold[48];
    int t = threadIdx.x;
    if (t < 48) {
        float s;
        if (t < 32) {                       // Wc[c][j]: c = t>>4, j = t&15
            int c = t >> 4, j = t & 15;
            s = 0.0f;
#pragma unroll
            for (int e = 0; e < 32; ++e)
                s = fmaf(W_se[c * 32 + e], W1[e * 16 + j], s);
        } else {                            // bc[j]
            int j = t - 32;
            s = b1[j];
#pragma unroll
            for (int e = 0; e < 32; ++e)
                s = fmaf(b_se[e], W1[e * 16 + j], s);
        }
        fold[t] = s;
    }
    __syncthreads();

    int tid = blockIdx.x * 256 + t;
    if (tid >= NODES * 8) return;
    int n  = tid >> 3;            // node
    int k0 = (tid & 7) * 4;       // 4-channel slice

    // ---- layer-1 weights as v2f pairs over j (8 each) ----
    v2f wc0v[8], wc1v[8], bcv[8];
    {
        const v2f* fv = (const v2f*)fold;
#pragma unroll
        for (int j = 0; j < 8; ++j) {
            wc0v[j] = fv[j];
            wc1v[j] = fv[8 + j];
            bcv[j]  = fv[16 + j];
        }
    }

    // ---- W2 slice: 16 rows x 4 ch as NAMED v2f pairs (no arrays) ----
#define W2LD(p)                                                              \
    float4 f4a_##p = *(const float4*)(W2 + (2 * (p)) * 32 + k0);             \
    float4 f4b_##p = *(const float4*)(W2 + (2 * (p) + 1) * 32 + k0);         \
    v2f w2a_##p##_0 = {f4a_##p.x, f4a_##p.y};                                \
    v2f w2b_##p##_0 = {f4a_##p.z, f4a_##p.w};                                \
    v2f w2a_##p##_1 = {f4b_##p.x, f4b_##p.y};                                \
    v2f w2b_##p##_1 = {f4b_##p.z, f4b_##p.w};
    W2LD(0) W2LD(1) W2LD(2) W2LD(3) W2LD(4) W2LD(5) W2LD(6) W2LD(7)
#undef W2LD

    v2f b2v0, b2v1;
    {
        float4 f4 = *(const float4*)(b2 + k0);
        b2v0.x = f4.x; b2v0.y = f4.y; b2v1.x = f4.z; b2v1.y = f4.w;
    }

    v2f vmax0 = splat2(0.0f), vmax1 = splat2(0.0f);   // relu/max fold
    v2f zero2 = splat2(0.0f);

    const float2* corrf = (const float2*)corr + (size_t)n * NA;
    const int*    neip  = nei + (size_t)n * (NDEG * 3) + 1;   // col1, stride 3

#define L2PAIR(p) do {                                                       \
        v2f hs0 = splat2(h1v[p].x);                                          \
        acc0 = pk_fma(hs0, w2a_##p##_0, acc0);                               \
        acc1 = pk_fma(hs0, w2b_##p##_0, acc1);                               \
        v2f hs1 = splat2(h1v[p].y);                                          \
        acc0 = pk_fma(hs1, w2a_##p##_1, acc0);                               \
        acc1 = pk_fma(hs1, w2b_##p##_1, acc1);                               \
    } while (0)

#define MLP_STEP(r0, r1) do {                                                \
        v2f r0s = splat2(r0), r1s = splat2(r1);                              \
        v2f h1v[8];                                                          \
        _Pragma("unroll")                                                    \
        for (int j = 0; j < 8; ++j)                                          \
            h1v[j] = pk_max(zero2,                                           \
                     pk_fma(r0s, wc0v[j], pk_fma(r1s, wc1v[j], bcv[j])));    \
        v2f acc0 = b2v0, acc1 = b2v1;                                        \
        L2PAIR(0); L2PAIR(1); L2PAIR(2); L2PAIR(3);                          \
        L2PAIR(4); L2PAIR(5); L2PAIR(6); L2PAIR(7);                          \
        vmax0 = pk_max(vmax0, acc0);                                         \
        vmax1 = pk_max(vmax1, acc1);                                         \
    } while (0)

    // ---- software-pipelined gather: idx 2 chunks ahead, rel 1 ahead ----
    int aA[4], aB[4];
    float2 rA[4], rB[4];
#pragma unroll
    for (int u = 0; u < 4; ++u) aA[u] = neip[u * 3];
#pragma unroll
    for (int u = 0; u < 4; ++u) aB[u] = neip[(4 + u) * 3];
#pragma unroll
    for (int u = 0; u < 4; ++u) rA[u] = corrf[aA[u]];

#pragma unroll
    for (int c = 0; c < 8; c += 2) {
#pragma unroll
        for (int u = 0; u < 4; ++u) rB[u] = corrf[aB[u]];
        if (c + 2 < 8) {
#pragma unroll
            for (int u = 0; u < 4; ++u) aA[u] = neip[((c + 2) * 4 + u) * 3];
        }
#pragma unroll
        for (int u = 0; u < 4; ++u) MLP_STEP(rA[u].x, rA[u].y);

        if (c + 2 < 8) {
#pragma unroll
            for (int u = 0; u < 4; ++u) rA[u] = corrf[aA[u]];
        }
        if (c + 3 < 8) {
#pragma unroll
            for (int u = 0; u < 4; ++u) aB[u] = neip[((c + 3) * 4 + u) * 3];
        }
#pragma unroll
        for (int u = 0; u < 4; ++u) MLP_STEP(rB[u].x, rB[u].y);
    }
#undef MLP_STEP
#undef L2PAIR

    // ---- coalesced store: wave writes 64 x 16B contiguous ----
    float4 o;
    o.x = vmax0.x; o.y = vmax0.y; o.z = vmax1.x; o.w = vmax1.y;
    *(float4*)(out + (size_t)n * 32 + k0) = o;
}

extern "C" void kernel_launch(void* const* d_in, const int* in_sizes, int n_in,
                              void* d_out, int out_size, void* d_ws, size_t ws_size,
                              hipStream_t stream) {
    const float* corr = (const float*)d_in[0];
    const int*   nei  = (const int*)d_in[1];
    // d_in[2] = lstm_state: dead input (unused by the reference output)
    const float* W_se = (const float*)d_in[3];
    const float* b_se = (const float*)d_in[4];
    const float* W1   = (const float*)d_in[5];
    const float* b1   = (const float*)d_in[6];
    const float* W2   = (const float*)d_in[7];
    const float* b2   = (const float*)d_in[8];
    float* out = (float*)d_out;

    int total  = NODES * 8;
    int blocks = (total + 255) / 256;
    hipLaunchKernelGGL(fused_kernel, dim3(blocks), dim3(256), 0, stream,
                       corr, nei, W_se, b_se, W1, b1, W2, b2, out);
}